// Round 3
// baseline (320.720 us; speedup 1.0000x reference)
//
#include <hip/hip_runtime.h>
#include <stdint.h>

// SoftALU, barrier-free one-wave-per-batch form — DECOMPOSITION PROBE ROUND.
//
// Kernel body is byte-identical to round 2 (276.2 us total). This round
// launches it TWICE (idempotent: same inputs -> same output, absmax
// unaffected). Purpose: measure T_warm = dur_new - 276.2, the kernel's
// steady-state duration (second run reads are L3-hot, writes nt to HBM).
//
//   T_warm ~ 36-50 us  => cold kernel ~ floor (46 us traffic bound);
//                         residual ~230 us is unconditional harness poison
//                         (2x 896 MiB fillBufferAligned @ ~145 us observed)
//                         => ROOFLINE.
//   T_warm >~ 70 us    => real store-path stall exists; attack it next.
//
// Rationale: rocprof top-5 is saturated by the harness fills, our dispatch
// never appears, and two serialized 145 us fills would exceed the 276 us
// total — the decomposition F_harness + T_kernel is unresolvable from
// counters alone. This probe resolves it with one bench.

typedef float vfloat4 __attribute__((ext_vector_type(4)));

__global__ __launch_bounds__(256) void softalu_wave(const float* __restrict__ a,
                                                    const float* __restrict__ b,
                                                    vfloat4* __restrict__ out,
                                                    int B) {
    const int wave_in_blk = threadIdx.x >> 6;
    const int lane = threadIdx.x & 63;
    const int batch = blockIdx.x * 4 + wave_in_blk;  // one wave per batch
    if (batch >= B) return;

    const vfloat4* a4 = (const vfloat4*)a + (size_t)batch * 256;
    const vfloat4* b4 = (const vfloat4*)b + (size_t)batch * 256;

    // ---- decode: build av, bv (wave-uniform scalars) ----
    uint32_t av = 0u, bv = 0u;
#pragma unroll
    for (int n = 0; n < 4; ++n) {
        const vfloat4 va = a4[n * 64 + lane];
        const vfloat4 vb = b4[n * 64 + lane];

        int ca = 0;
        bool ha = false;
        if (va.x > 0.5f) { ha = true; ca = lane * 4 + 0; }
        if (va.y > 0.5f) { ha = true; ca = lane * 4 + 1; }
        if (va.z > 0.5f) { ha = true; ca = lane * 4 + 2; }
        if (va.w > 0.5f) { ha = true; ca = lane * 4 + 3; }

        int cb = 0;
        bool hb = false;
        if (vb.x > 0.5f) { hb = true; cb = lane * 4 + 0; }
        if (vb.y > 0.5f) { hb = true; cb = lane * 4 + 1; }
        if (vb.z > 0.5f) { hb = true; cb = lane * 4 + 2; }
        if (vb.w > 0.5f) { hb = true; cb = lane * 4 + 3; }

        // exactly one lane is hot per one-hot row
        const unsigned long long ma = __ballot(ha);
        const unsigned long long mb = __ballot(hb);
        const int La = __ffsll((unsigned long long)ma) - 1;
        const int Lb = __ffsll((unsigned long long)mb) - 1;
        av |= ((uint32_t)__builtin_amdgcn_readlane(ca, La)) << (8 * n);
        bv |= ((uint32_t)__builtin_amdgcn_readlane(cb, Lb)) << (8 * n);
    }

    // ---- 7 ALU results (wave-uniform) ----
    uint32_t res[7];
    res[0] = av + bv;              // soft_add(a,b)
    res[1] = av - bv;              // a + negate(b) = a - b mod 2^32
    res[2] = av * bv;              // wrapping mul
    res[3] = bv ? (av / bv) : 0u;  // div, 0 when b==0
    res[4] = av & bv;
    res[5] = av | bv;
    res[6] = av ^ bv;

    // ---- emit: out float4 index = (op*B + batch)*256 + n*64 + lane ----
    const int c0 = lane * 4;
#pragma unroll
    for (int op = 0; op < 7; ++op) {
        const uint32_t r = res[op];
        vfloat4* orow = out + ((size_t)op * B + batch) * 256;
#pragma unroll
        for (int n = 0; n < 4; ++n) {
            const int rb = (int)((r >> (8 * n)) & 255u);
            vfloat4 v;
            v.x = (c0 + 0 == rb) ? 1.0f : 0.0f;
            v.y = (c0 + 1 == rb) ? 1.0f : 0.0f;
            v.z = (c0 + 2 == rb) ? 1.0f : 0.0f;
            v.w = (c0 + 3 == rb) ? 1.0f : 0.0f;
            __builtin_nontemporal_store(v, &orow[n * 64 + lane]);
        }
    }
}

extern "C" void kernel_launch(void* const* d_in, const int* in_sizes, int n_in,
                              void* d_out, int out_size, void* d_ws, size_t ws_size,
                              hipStream_t stream) {
    const float* a = (const float*)d_in[0];
    const float* b = (const float*)d_in[1];
    const int B = in_sizes[0] / (4 * 256);  // 8192
    (void)d_ws; (void)ws_size;

    // PROBE: double launch. Second run is idempotent; its marginal cost in
    // dur_us measures the kernel's warm steady-state time (see header).
    softalu_wave<<<(B + 3) / 4, 256, 0, stream>>>(a, b, (vfloat4*)d_out, B);
    softalu_wave<<<(B + 3) / 4, 256, 0, stream>>>(a, b, (vfloat4*)d_out, B);
}

// Round 4
// 277.286 us; speedup vs baseline: 1.1566x; 1.1566x over previous
//
#include <hip/hip_runtime.h>
#include <stdint.h>

// SoftALU, barrier-free one-wave-per-batch form. FINAL (revert of the round-3
// double-launch decomposition probe; body identical to round 2's 276.2 us run).
//
// Inputs are EXACT one-hot byte encodings; softmax(100*x) collapses to hard
// integer ALU. Pipeline: decode one-hot -> uint32 a,b; compute
// {+, -, *, /, &, |, ^}; re-emit one-hot.
//
// Measured decomposition (round-3 probe, double-launch):
//   T_warm = 320.7 - 276.2 = 44.5 us for the second (idempotent) launch
//          = 224 MiB nt-store @ 5.3 TB/s (81% of the harness's own 6.5 TB/s
//            fill rate, while also carrying the 64 MiB decode read).
//   Cold per-iteration kernel ~ 50-55 us vs 46 us traffic floor.
//   Residual ~225 us of dur_us is UNCONDITIONAL harness poison: 2x 896 MiB
//   fillBufferAligned (~145 us each, partially overlapped) + out poison +
//   input restore. Round 1 proved usage-independence (dropping all d_ws use
//   changed nothing). Remaining kernel headroom <= ~10 us (~3% of total).
//
// Structure (why it's at floor):
//  - one 64-lane wave owns one batch (4 waves/block, grid = B/4); no LDS,
//    no __syncthreads, no serial section anywhere
//  - decode: 8 coalesced float4 loads/lane, per-row __ballot + __ffsll +
//    readlane extracts the hot byte on the scalar pipe
//  - 7 results computed wave-uniformly (incl. the u32 divide)
//  - emit: 28 independent nontemporal 16 B stores/lane; each (op,row) is a
//    contiguous 1 KiB wave store; 32 waves/CU keep the store pipe saturated

typedef float vfloat4 __attribute__((ext_vector_type(4)));

__global__ __launch_bounds__(256) void softalu_wave(const float* __restrict__ a,
                                                    const float* __restrict__ b,
                                                    vfloat4* __restrict__ out,
                                                    int B) {
    const int wave_in_blk = threadIdx.x >> 6;
    const int lane = threadIdx.x & 63;
    const int batch = blockIdx.x * 4 + wave_in_blk;  // one wave per batch
    if (batch >= B) return;

    const vfloat4* a4 = (const vfloat4*)a + (size_t)batch * 256;
    const vfloat4* b4 = (const vfloat4*)b + (size_t)batch * 256;

    // ---- decode: build av, bv (wave-uniform scalars) ----
    uint32_t av = 0u, bv = 0u;
#pragma unroll
    for (int n = 0; n < 4; ++n) {
        const vfloat4 va = a4[n * 64 + lane];
        const vfloat4 vb = b4[n * 64 + lane];

        int ca = 0;
        bool ha = false;
        if (va.x > 0.5f) { ha = true; ca = lane * 4 + 0; }
        if (va.y > 0.5f) { ha = true; ca = lane * 4 + 1; }
        if (va.z > 0.5f) { ha = true; ca = lane * 4 + 2; }
        if (va.w > 0.5f) { ha = true; ca = lane * 4 + 3; }

        int cb = 0;
        bool hb = false;
        if (vb.x > 0.5f) { hb = true; cb = lane * 4 + 0; }
        if (vb.y > 0.5f) { hb = true; cb = lane * 4 + 1; }
        if (vb.z > 0.5f) { hb = true; cb = lane * 4 + 2; }
        if (vb.w > 0.5f) { hb = true; cb = lane * 4 + 3; }

        // exactly one lane is hot per one-hot row
        const unsigned long long ma = __ballot(ha);
        const unsigned long long mb = __ballot(hb);
        const int La = __ffsll((unsigned long long)ma) - 1;
        const int Lb = __ffsll((unsigned long long)mb) - 1;
        av |= ((uint32_t)__builtin_amdgcn_readlane(ca, La)) << (8 * n);
        bv |= ((uint32_t)__builtin_amdgcn_readlane(cb, Lb)) << (8 * n);
    }

    // ---- 7 ALU results (wave-uniform) ----
    uint32_t res[7];
    res[0] = av + bv;              // soft_add(a,b)
    res[1] = av - bv;              // a + negate(b) = a - b mod 2^32
    res[2] = av * bv;              // wrapping mul
    res[3] = bv ? (av / bv) : 0u;  // div, 0 when b==0
    res[4] = av & bv;
    res[5] = av | bv;
    res[6] = av ^ bv;

    // ---- emit: out float4 index = (op*B + batch)*256 + n*64 + lane ----
    const int c0 = lane * 4;
#pragma unroll
    for (int op = 0; op < 7; ++op) {
        const uint32_t r = res[op];
        vfloat4* orow = out + ((size_t)op * B + batch) * 256;
#pragma unroll
        for (int n = 0; n < 4; ++n) {
            const int rb = (int)((r >> (8 * n)) & 255u);
            vfloat4 v;
            v.x = (c0 + 0 == rb) ? 1.0f : 0.0f;
            v.y = (c0 + 1 == rb) ? 1.0f : 0.0f;
            v.z = (c0 + 2 == rb) ? 1.0f : 0.0f;
            v.w = (c0 + 3 == rb) ? 1.0f : 0.0f;
            __builtin_nontemporal_store(v, &orow[n * 64 + lane]);
        }
    }
}

extern "C" void kernel_launch(void* const* d_in, const int* in_sizes, int n_in,
                              void* d_out, int out_size, void* d_ws, size_t ws_size,
                              hipStream_t stream) {
    const float* a = (const float*)d_in[0];
    const float* b = (const float*)d_in[1];
    const int B = in_sizes[0] / (4 * 256);  // 8192
    (void)d_ws; (void)ws_size;
    softalu_wave<<<(B + 3) / 4, 256, 0, stream>>>(a, b, (vfloat4*)d_out, B);
}